// Round 7
// baseline (1423.459 us; speedup 1.0000x reference)
//
#include <hip/hip_runtime.h>

typedef __attribute__((ext_vector_type(8))) short s8v;
typedef __attribute__((ext_vector_type(4))) short s4v;
typedef __attribute__((ext_vector_type(4))) float f4v;

#if __has_builtin(__builtin_amdgcn_exp2f)
#define EXP2(x) __builtin_amdgcn_exp2f(x)
#else
#define EXP2(x) exp2f(x)
#endif
#if __has_builtin(__builtin_amdgcn_rcpf)
#define RCP(x) __builtin_amdgcn_rcpf(x)
#else
#define RCP(x) (1.0f/(x))
#endif

#define LOG2E 1.4426950408889634f
#define NBLK 192

__device__ __forceinline__ short f2bf(float f) {
    union { float f; unsigned u; } x; x.f = f;
    unsigned r = (x.u + 0x7FFFu + ((x.u >> 16) & 1u)) >> 16;
    return (short)r;
}
__device__ __forceinline__ float bf2f(short s) {
    union { unsigned u; float f; } x; x.u = ((unsigned)(unsigned short)s) << 16;
    return x.f;
}
// LDS-visibility barrier WITHOUT vmcnt drain (keeps prefetch/stores in flight).
__device__ __forceinline__ void lds_barrier() {
    asm volatile("s_waitcnt lgkmcnt(0)\n\ts_barrier" ::: "memory");
}
// Grid-wide barrier: release fence -> per-block arrive -> spin -> acquire fence.
// __threadfence() at agent scope emits buffer_wbl2 / buffer_inv on gfx950,
// giving cross-XCD visibility for the pipeline buffers.
__device__ __forceinline__ void grid_sync(int* ctr, int slot, int tid) {
    __threadfence();
    __syncthreads();
    if (tid == 0) {
        __hip_atomic_fetch_add(&ctr[slot], 1, __ATOMIC_ACQ_REL, __HIP_MEMORY_SCOPE_AGENT);
        while (__hip_atomic_load(&ctr[slot], __ATOMIC_RELAXED, __HIP_MEMORY_SCOPE_AGENT) < NBLK)
            __builtin_amdgcn_s_sleep(2);
    }
    __syncthreads();
    __threadfence();
}

// ---------------- prep (weights->bf16 B-frag, sigmoid pre-scale) + embed MLP, fused ----------------
__global__ __launch_bounds__(256) void prep_embed_kernel(
        const float* __restrict__ k1f, const float* __restrict__ r1f,
        const float* __restrict__ k1b, const float* __restrict__ r1b,
        const float* __restrict__ k2f, const float* __restrict__ r2f,
        const float* __restrict__ k2b, const float* __restrict__ r2b,
        short* __restrict__ WB1, short* __restrict__ WB2,
        const int* __restrict__ inputA, const float* __restrict__ emb,
        const float* __restrict__ w1, const float* __restrict__ b1,
        const float* __restrict__ w2, const float* __restrict__ b2,
        const float* __restrict__ w3, const float* __restrict__ b3,
        float* __restrict__ xe) {
    if (blockIdx.x < 1024) {
        int idx = blockIdx.x * 256 + threadIdx.x;
        if (idx < 262144) {  // 2*32*8*64*8
            int j = idx & 7, l = (idx >> 3) & 63, c = (idx >> 9) & 7, n = (idx >> 12) & 31, d = (idx >> 17) & 1;
            int coln = n * 16 + (l & 15);
            int k = c * 32 + ((l >> 4) * 8) + j;
            const float* Wk = d ? k1b : k1f;
            const float* Wr = d ? r1b : r1f;
            float v = (c < 4) ? Wk[k * 512 + coln] : Wr[(k - 128) * 512 + coln];
            float sc = ((n >> 3) == 2) ? 1.0f : -LOG2E;  // gate: 0=i,1=f,2=cc,3=o
            WB1[idx] = f2bf(v * sc);
        }
        if (idx < 163840) {  // 2*16*10*64*8
            int d = idx / 81920, r0 = idx % 81920;
            int n = r0 / 5120, r1 = r0 % 5120;
            int c = r1 / 512, li = r1 % 512;
            int l = li >> 3, j = li & 7;
            int coln = n * 16 + (l & 15);
            int k = c * 32 + ((l >> 4) * 8) + j;
            const float* Wk = d ? k2b : k2f;
            const float* Wr = d ? r2b : r2f;
            float v = (k < 256) ? Wk[k * 256 + coln] : Wr[(k - 256) * 256 + coln];
            float sc = ((n >> 2) == 2) ? 1.0f : -LOG2E;
            WB2[idx] = f2bf(v * sc);
        }
        return;
    }
    __shared__ float row[600];
    __shared__ float h1[256];
    __shared__ float h2[128];
    int b = blockIdx.x - 1024, t = threadIdx.x;
    if (t < 200) {
        int idx = inputA[b * 200 + t];
        row[t * 3 + 0] = emb[idx * 3 + 0];
        row[t * 3 + 1] = emb[idx * 3 + 1];
        row[t * 3 + 2] = emb[idx * 3 + 2];
    }
    __syncthreads();
    float a = b1[t];
    for (int k = 0; k < 600; k++) a += row[k] * w1[k * 256 + t];
    h1[t] = fmaxf(a, 0.f);
    __syncthreads();
    if (t < 128) {
        float a2 = b2[t];
        for (int k = 0; k < 256; k++) a2 += h1[k] * w2[k * 128 + t];
        h2[t] = fmaxf(a2, 0.f);
    }
    __syncthreads();
    if (t < 64) {
        float a3 = b3[t];
        for (int k = 0; k < 128; k++) a3 += h2[k] * w3[k * 64 + t];
        xe[b * 64 + t] = fmaxf(a3, 0.f);
    }
}

// ---------------- persistent pipeline kernel ----------------
// 192 blocks x 512 threads, 88KB static LDS -> exactly 1 block/CU, all co-resident.
// blocks 0..31:  lstm1 chains (persistent h in LDS, c in regs)
// blocks 32..63: lstm2 chains (waves 0-3 compute, 4-7 barrier-follow)
// blocks 64..191: gemm workers
// super-step k: gemm1(k) | lstm1(k-1) | gemm2(k-2) | lstm2(k-3), grid_sync between.
__global__ __launch_bounds__(512, 2) void persist_kernel(
        const float* __restrict__ x, const short* __restrict__ WB1, const short* __restrict__ WB2,
        const float* __restrict__ bb1f, const float* __restrict__ bb1b,
        const float* __restrict__ bb2f, const float* __restrict__ bb2b,
        short* __restrict__ yfr, short* __restrict__ xgA, short* __restrict__ xgB,
        short* __restrict__ ygA, short* __restrict__ ygB,
        float* __restrict__ h2o, int* __restrict__ syncp, int TC, int NC) {
    __shared__ short hA[2048];
    __shared__ short hB[2048];
    __shared__ short axf[16384];
    __shared__ char pad[49152];   // static pad: 40KB + 48KB = 88KB -> 1 block/CU
    const int tid = threadIdx.x, lane = tid & 63, w = tid >> 6;
    const int bid = blockIdx.x;
    const int NSTEP = NC + 3;
    if (TC == 0) pad[tid] = 0;    // keep pad alive (never true)

    if (bid < 32) {
        // ================= LSTM1 persistent chain =================
        const int btile = bid & 15, dir = bid >> 4;
        const int col = lane & 15, q = lane >> 4, u = (w << 4) + col;
        const int sb = dir * 16 + btile;
        s8v wf[4][4];  // h-part chunks 4..7
#pragma unroll
        for (int ti = 0; ti < 4; ti++)
#pragma unroll
            for (int c = 0; c < 4; c++)
                wf[ti][c] = *(const s8v*)(WB1 + ((((dir * 32 + (w + 8 * ti)) * 8) + 4 + c) * 64 + lane) * 8);
        float cst[4] = {0.f, 0.f, 0.f, 0.f}, hl[4];
        for (int i = tid; i < 2048; i += 512) hA[i] = 0;
        __syncthreads();
        const int hidx = (w >> 1) * 512 + ((u >> 3) & 3) * 128 + (u & 7);

        for (int k = 0; k < NSTEP; k++) {
            const int c = k - 1;
            if (c >= 0 && c < NC) {
                const int t0 = c * TC;
                const short* xgp = ((c & 1) ? xgB : xgA) + (size_t)sb * TC * 8192 + w * 1024 + lane * 8;
                s8v pe0 = *(const s8v*)(xgp);
                s8v pe1 = *(const s8v*)(xgp + 512);
                s8v po0 = *(const s8v*)(xgp + 8192);
                s8v po1 = *(const s8v*)(xgp + 8192 + 512);
                for (int s = 0; s < TC; s += 2) {
                    {   // even step: read hA, write hB
                        s8v ah[4];
#pragma unroll
                        for (int cc = 0; cc < 4; cc++) ah[cc] = *(const s8v*)&hA[(cc * 64 + lane) * 8];
                        if (w >= 4 && s > 0) {
                            int tp = t0 + s - 1;
                            if (dir) tp = 511 - tp;
                            s8v hv = (w == 4) ? ah[0] : (w == 5) ? ah[1] : (w == 6) ? ah[2] : ah[3];
                            *(s8v*)(yfr + (((size_t)(btile * 512 + tp) * 8) + dir * 4 + (w - 4)) * 512 + lane * 8) = hv;
                        }
                        f4v acc[4];
#pragma unroll
                        for (int r = 0; r < 4; r++) {
                            acc[0][r] = bf2f(pe0[r]);
                            acc[1][r] = bf2f(pe0[4 + r]);
                            acc[2][r] = bf2f(pe1[r]);
                            acc[3][r] = bf2f(pe1[4 + r]);
                        }
                        {
                            const short* np = xgp + (size_t)(s + 2) * 8192;
                            pe0 = *(const s8v*)np;
                            pe1 = *(const s8v*)(np + 512);
                        }
#pragma unroll
                        for (int cc = 0; cc < 4; cc++)
#pragma unroll
                            for (int ti = 0; ti < 4; ti++)
                                acc[ti] = __builtin_amdgcn_mfma_f32_16x16x32_bf16(ah[cc], wf[ti][cc], acc[ti], 0, 0, 0);
#pragma unroll
                        for (int r = 0; r < 4; r++) {
                            float iv = RCP(1.0f + EXP2(acc[0][r]));
                            float fv = RCP(1.0f + EXP2(acc[1][r]));
                            float ov = RCP(1.0f + EXP2(acc[3][r]));
                            float ccv = fmaxf(acc[2][r], 0.f);
                            cst[r] = fv * cst[r] + iv * ccv;
                            hl[r] = ov * fmaxf(cst[r], 0.f);
                        }
#pragma unroll
                        for (int r = 0; r < 4; r++)
                            hB[hidx + ((q * 4 + r) << 3)] = f2bf(hl[r]);
                        lds_barrier();
                    }
                    {   // odd step: read hB, write hA
                        s8v ah[4];
#pragma unroll
                        for (int cc = 0; cc < 4; cc++) ah[cc] = *(const s8v*)&hB[(cc * 64 + lane) * 8];
                        if (w >= 4) {
                            int tp = t0 + s;
                            if (dir) tp = 511 - tp;
                            s8v hv = (w == 4) ? ah[0] : (w == 5) ? ah[1] : (w == 6) ? ah[2] : ah[3];
                            *(s8v*)(yfr + (((size_t)(btile * 512 + tp) * 8) + dir * 4 + (w - 4)) * 512 + lane * 8) = hv;
                        }
                        f4v acc[4];
#pragma unroll
                        for (int r = 0; r < 4; r++) {
                            acc[0][r] = bf2f(po0[r]);
                            acc[1][r] = bf2f(po0[4 + r]);
                            acc[2][r] = bf2f(po1[r]);
                            acc[3][r] = bf2f(po1[4 + r]);
                        }
                        {
                            const short* np = xgp + (size_t)(s + 3) * 8192;
                            po0 = *(const s8v*)np;
                            po1 = *(const s8v*)(np + 512);
                        }
#pragma unroll
                        for (int cc = 0; cc < 4; cc++)
#pragma unroll
                            for (int ti = 0; ti < 4; ti++)
                                acc[ti] = __builtin_amdgcn_mfma_f32_16x16x32_bf16(ah[cc], wf[ti][cc], acc[ti], 0, 0, 0);
#pragma unroll
                        for (int r = 0; r < 4; r++) {
                            float iv = RCP(1.0f + EXP2(acc[0][r]));
                            float fv = RCP(1.0f + EXP2(acc[1][r]));
                            float ov = RCP(1.0f + EXP2(acc[3][r]));
                            float ccv = fmaxf(acc[2][r], 0.f);
                            cst[r] = fv * cst[r] + iv * ccv;
                            hl[r] = ov * fmaxf(cst[r], 0.f);
                        }
#pragma unroll
                        for (int r = 0; r < 4; r++)
                            hA[hidx + ((q * 4 + r) << 3)] = f2bf(hl[r]);
                        lds_barrier();
                    }
                }
                if (w >= 4) {  // final h(TC-1) of this chunk
                    int tp = t0 + TC - 1;
                    if (dir) tp = 511 - tp;
                    s8v hv = *(const s8v*)&hA[((w - 4) * 64 + lane) * 8];
                    *(s8v*)(yfr + (((size_t)(btile * 512 + tp) * 8) + dir * 4 + (w - 4)) * 512 + lane * 8) = hv;
                }
            }
            grid_sync(syncp, k, tid);
        }
    } else if (bid < 64) {
        // ================= LSTM2 persistent chain (waves 0-3 compute) =================
        const int btile = (bid - 32) & 15, dir = (bid - 32) >> 4;
        const int b0 = btile << 4;
        const int w4 = w & 3;
        const int col = lane & 15, q = lane >> 4, u = (w4 << 4) + col;
        const int sb = dir * 16 + btile;
        s8v wf[4][2];  // h-part chunks 8,9 (w>=4 loads same as w-4; unused)
#pragma unroll
        for (int ti = 0; ti < 4; ti++)
#pragma unroll
            for (int c = 0; c < 2; c++)
                wf[ti][c] = *(const s8v*)(WB2 + ((((dir * 16 + (w4 + 4 * ti)) * 10) + 8 + c) * 64 + lane) * 8);
        float cst[4] = {0.f, 0.f, 0.f, 0.f}, hl[4] = {0.f, 0.f, 0.f, 0.f};
        for (int i = tid; i < 1024; i += 512) hA[i] = 0;
        __syncthreads();
        const int hidx = (w4 >> 1) * 512 + ((u >> 3) & 3) * 128 + (u & 7);

        for (int k = 0; k < NSTEP; k++) {
            const int c = k - 3;
            if (c >= 0 && c < NC) {
                const short* ygp = ((c & 1) ? ygB : ygA) + (size_t)sb * TC * 4096 + w4 * 1024 + lane * 8;
                s8v pe0, pe1, po0, po1;
                if (w < 4) {
                    pe0 = *(const s8v*)(ygp);
                    pe1 = *(const s8v*)(ygp + 512);
                    po0 = *(const s8v*)(ygp + 4096);
                    po1 = *(const s8v*)(ygp + 4096 + 512);
                }
                for (int s = 0; s < TC; s += 2) {
                    if (w < 4) {  // even: read hA, write hB
                        s8v ah[2];
#pragma unroll
                        for (int cc = 0; cc < 2; cc++) ah[cc] = *(const s8v*)&hA[(cc * 64 + lane) * 8];
                        f4v acc[4];
#pragma unroll
                        for (int r = 0; r < 4; r++) {
                            acc[0][r] = bf2f(pe0[r]);
                            acc[1][r] = bf2f(pe0[4 + r]);
                            acc[2][r] = bf2f(pe1[r]);
                            acc[3][r] = bf2f(pe1[4 + r]);
                        }
                        {
                            const short* np = ygp + (size_t)(s + 2) * 4096;
                            pe0 = *(const s8v*)np;
                            pe1 = *(const s8v*)(np + 512);
                        }
#pragma unroll
                        for (int cc = 0; cc < 2; cc++)
#pragma unroll
                            for (int ti = 0; ti < 4; ti++)
                                acc[ti] = __builtin_amdgcn_mfma_f32_16x16x32_bf16(ah[cc], wf[ti][cc], acc[ti], 0, 0, 0);
#pragma unroll
                        for (int r = 0; r < 4; r++) {
                            float iv = RCP(1.0f + EXP2(acc[0][r]));
                            float fv = RCP(1.0f + EXP2(acc[1][r]));
                            float ov = RCP(1.0f + EXP2(acc[3][r]));
                            float ccv = fmaxf(acc[2][r], 0.f);
                            cst[r] = fv * cst[r] + iv * ccv;
                            hl[r] = ov * fmaxf(cst[r], 0.f);
                        }
#pragma unroll
                        for (int r = 0; r < 4; r++)
                            hB[hidx + ((q * 4 + r) << 3)] = f2bf(hl[r]);
                    }
                    lds_barrier();
                    if (w < 4) {  // odd: read hB, write hA
                        s8v ah[2];
#pragma unroll
                        for (int cc = 0; cc < 2; cc++) ah[cc] = *(const s8v*)&hB[(cc * 64 + lane) * 8];
                        f4v acc[4];
#pragma unroll
                        for (int r = 0; r < 4; r++) {
                            acc[0][r] = bf2f(po0[r]);
                            acc[1][r] = bf2f(po0[4 + r]);
                            acc[2][r] = bf2f(po1[r]);
                            acc[3][r] = bf2f(po1[4 + r]);
                        }
                        {
                            const short* np = ygp + (size_t)(s + 3) * 4096;
                            po0 = *(const s8v*)np;
                            po1 = *(const s8v*)(np + 512);
                        }
#pragma unroll
                        for (int cc = 0; cc < 2; cc++)
#pragma unroll
                            for (int ti = 0; ti < 4; ti++)
                                acc[ti] = __builtin_amdgcn_mfma_f32_16x16x32_bf16(ah[cc], wf[ti][cc], acc[ti], 0, 0, 0);
#pragma unroll
                        for (int r = 0; r < 4; r++) {
                            float iv = RCP(1.0f + EXP2(acc[0][r]));
                            float fv = RCP(1.0f + EXP2(acc[1][r]));
                            float ov = RCP(1.0f + EXP2(acc[3][r]));
                            float ccv = fmaxf(acc[2][r], 0.f);
                            cst[r] = fv * cst[r] + iv * ccv;
                            hl[r] = ov * fmaxf(cst[r], 0.f);
                        }
#pragma unroll
                        for (int r = 0; r < 4; r++)
                            hA[hidx + ((q * 4 + r) << 3)] = f2bf(hl[r]);
                    }
                    lds_barrier();
                }
                if (c == NC - 1 && w < 4) {
#pragma unroll
                    for (int r = 0; r < 4; r++)
                        h2o[((dir * 256) + b0 + q * 4 + r) * 64 + u] = hl[r];
                }
            }
            grid_sync(syncp, k, tid);
        }
    } else {
        // ================= GEMM workers =================
        const int wid = bid - 64;  // 0..127
        const int tgn = TC >> 3;   // 8 (TC=64) or 4 (TC=32)
        const int ng = tgn << 5;   // groups per chunk (both dirs)
        for (int k = 0; k < NSTEP; k++) {
            const int cg1 = k;
            if (cg1 < NC) {  // ---- gemm1: xg(cg1) = x @ Wk + b ----
                const int t0 = cg1 * TC;
                short* xg_w = (cg1 & 1) ? xgB : xgA;
                for (int g = wid; g < ng; g += 128) {
                    const int btile = g & 15;
                    const int rest = g >> 4;
                    const int tg = rest & (tgn - 1);
                    const int dir = (rest >= tgn) ? 1 : 0;
                    const int b0 = btile << 4;
                    __syncthreads();  // axf reuse across groups
                    {   // stage A frags for slice sl = w (coalesced + XOR swizzle)
                        int tglob = t0 + tg * 8 + w;
                        if (dir) tglob = 511 - tglob;
                        const int half = lane >> 5;
                        const int f0 = (lane & 31) * 4;
                        const int cx = f0 >> 5, qq = (f0 >> 3) & 3, j0 = f0 & 7;
#pragma unroll
                        for (int rr = 0; rr < 8; rr++) {
                            const int m = rr * 2 + half;
                            const float* xp = x + ((size_t)(b0 + m) * 512 + tglob) * 128 + f0;
                            f4v v4 = *(const f4v*)xp;
                            const int slot = (qq << 4) | ((m ^ qq ^ (cx << 1)) & 15);
                            s4v pk;
#pragma unroll
                            for (int j = 0; j < 4; j++) pk[j] = f2bf(v4[j]);
                            *(s4v*)&axf[(((w * 4 + cx) * 64 + slot) * 8) + j0] = pk;
                        }
                    }
                    s8v wf[4][4];
#pragma unroll
                    for (int ti = 0; ti < 4; ti++)
#pragma unroll
                        for (int c = 0; c < 4; c++)
                            wf[ti][c] = *(const s8v*)(WB1 + ((((dir * 32 + (w + 8 * ti)) * 8) + c) * 64 + lane) * 8);
                    const float* bb = dir ? bb1b : bb1f;
                    float bias[4];
#pragma unroll
                    for (int ti = 0; ti < 4; ti++) {
                        const int tile = w + 8 * ti;
                        float sc = ((tile >> 3) == 2) ? 1.0f : -LOG2E;
                        bias[ti] = sc * bb[tile * 16 + (lane & 15)];
                    }
                    __syncthreads();
                    const size_t sb = dir * 16 + btile;
#pragma unroll 2
                    for (int sl = 0; sl < 8; sl++) {
                        s8v a[4];
#pragma unroll
                        for (int c = 0; c < 4; c++) {
                            const int slot = lane ^ (lane >> 4) ^ (c << 1);
                            a[c] = *(const s8v*)&axf[((sl * 4 + c) * 64 + slot) * 8];
                        }
                        f4v acc[4];
#pragma unroll
                        for (int ti = 0; ti < 4; ti++) { f4v z = {0.f, 0.f, 0.f, 0.f}; acc[ti] = z; }
#pragma unroll
                        for (int c = 0; c < 4; c++)
#pragma unroll
                            for (int ti = 0; ti < 4; ti++)
                                acc[ti] = __builtin_amdgcn_mfma_f32_16x16x32_bf16(a[c], wf[ti][c], acc[ti], 0, 0, 0);
                        short* outp = xg_w + ((sb * TC + (size_t)(tg * 8 + sl)) * 8 + w) * 1024 + lane * 8;
#pragma unroll
                        for (int p = 0; p < 2; p++) {
                            s8v v;
#pragma unroll
                            for (int j = 0; j < 4; j++) {
                                v[j]     = f2bf(acc[2 * p][j]     + bias[2 * p]);
                                v[4 + j] = f2bf(acc[2 * p + 1][j] + bias[2 * p + 1]);
                            }
                            *(s8v*)(outp + p * 512) = v;
                        }
                    }
                }
            }
            const int cg2 = k - 2;
            if (cg2 >= 0 && cg2 < NC) {  // ---- gemm2: yg(cg2) = y @ Wk2 + b ----
                const int t0 = cg2 * TC;
                short* yg_w = (cg2 & 1) ? ygB : ygA;
                const int w4 = w & 3, sh = (w >> 2) * 4;
                for (int g = wid; g < ng; g += 128) {
                    const int btile = g & 15;
                    const int rest = g >> 4;
                    const int tg = rest & (tgn - 1);
                    const int dir = (rest >= tgn) ? 1 : 0;
                    s8v wf[4][8];
#pragma unroll
                    for (int ti = 0; ti < 4; ti++)
#pragma unroll
                        for (int c = 0; c < 8; c++)
                            wf[ti][c] = *(const s8v*)(WB2 + ((((dir * 16 + (w4 + 4 * ti)) * 10) + c) * 64 + lane) * 8);
                    const float* bb = dir ? bb2b : bb2f;
                    float bias[4];
#pragma unroll
                    for (int ti = 0; ti < 4; ti++) {
                        const int tile = w4 + 4 * ti;
                        float sc = ((tile >> 2) == 2) ? 1.0f : -LOG2E;
                        bias[ti] = sc * bb[tile * 16 + (lane & 15)];
                    }
                    const size_t sb = dir * 16 + btile;
#pragma unroll
                    for (int si = 0; si < 4; si++) {
                        const int sl = sh + si;
                        int tglob = t0 + tg * 8 + sl;
                        if (dir) tglob = 511 - tglob;
                        s8v a[8];
#pragma unroll
                        for (int c = 0; c < 8; c++)
                            a[c] = *(const s8v*)(yfr + (((size_t)(btile * 512 + tglob) * 8) + c) * 512 + lane * 8);
                        f4v acc[4];
#pragma unroll
                        for (int ti = 0; ti < 4; ti++) { f4v z = {0.f, 0.f, 0.f, 0.f}; acc[ti] = z; }
#pragma unroll
                        for (int c = 0; c < 8; c++)
#pragma unroll
                            for (int ti = 0; ti < 4; ti++)
                                acc[ti] = __builtin_amdgcn_mfma_f32_16x16x32_bf16(a[c], wf[ti][c], acc[ti], 0, 0, 0);
                        short* outp = yg_w + ((sb * TC + (size_t)(tg * 8 + sl)) * 4 + w4) * 1024 + lane * 8;
#pragma unroll
                        for (int p = 0; p < 2; p++) {
                            s8v v;
#pragma unroll
                            for (int j = 0; j < 4; j++) {
                                v[j]     = f2bf(acc[2 * p][j]     + bias[2 * p]);
                                v[4 + j] = f2bf(acc[2 * p + 1][j] + bias[2 * p + 1]);
                            }
                            *(s8v*)(outp + p * 512) = v;
                        }
                    }
                }
            }
            grid_sync(syncp, k, tid);
        }
    }
}

// ---------------- final heads (fp32) ----------------
__global__ void heads_kernel(const float* __restrict__ xe, const float* __restrict__ h2o,
                             const float* __restrict__ wz1, const float* __restrict__ bz1,
                             const float* __restrict__ wz2, const float* __restrict__ bz2,
                             const float* __restrict__ wt1, const float* __restrict__ bt1,
                             const float* __restrict__ wt2, const float* __restrict__ bt2,
                             float* __restrict__ out) {
    int b = threadIdx.x;  // 256 threads, 1 block
    float cz0 = bz1[0], cz1 = bz1[1], ct0 = bt1[0], ct1 = bt1[1];
    for (int k = 0; k < 192; k++) {
        float v = (k < 64) ? xe[b * 64 + k]
                : (k < 128) ? h2o[b * 64 + (k - 64)]
                            : h2o[(256 + b) * 64 + (k - 128)];
        cz0 += v * wz1[k * 2 + 0];
        cz1 += v * wz1[k * 2 + 1];
        ct0 += v * wt1[k * 2 + 0];
        ct1 += v * wt1[k * 2 + 1];
    }
    cz0 = fmaxf(cz0, 0.f); cz1 = fmaxf(cz1, 0.f);
    ct0 = fmaxf(ct0, 0.f); ct1 = fmaxf(ct1, 0.f);
    out[b] = cz0 * wz2[0] + cz1 * wz2[1] + bz2[0];
    out[256 + b] = ct0 * wt2[0] + ct1 * wt2[1] + bt2[0];
}

extern "C" void kernel_launch(void* const* d_in, const int* in_sizes, int n_in,
                              void* d_out, int out_size, void* d_ws, size_t ws_size,
                              hipStream_t stream) {
    const int*   inputA = (const int*)d_in[0];
    const float* inputB = (const float*)d_in[1];
    const float* emb = (const float*)d_in[2];
    const float* w1  = (const float*)d_in[3];
    const float* b1  = (const float*)d_in[4];
    const float* w2  = (const float*)d_in[5];
    const float* b2  = (const float*)d_in[6];
    const float* w3  = (const float*)d_in[7];
    const float* b3  = (const float*)d_in[8];
    const float* k1f = (const float*)d_in[9];
    const float* r1f = (const float*)d_in[10];
    const float* bb1f= (const float*)d_in[11];
    const float* k1b = (const float*)d_in[12];
    const float* r1b = (const float*)d_in[13];
    const float* bb1b= (const float*)d_in[14];
    const float* k2f = (const float*)d_in[15];
    const float* r2f = (const float*)d_in[16];
    const float* bb2f= (const float*)d_in[17];
    const float* k2b = (const float*)d_in[18];
    const float* r2b = (const float*)d_in[19];
    const float* bb2b= (const float*)d_in[20];
    const float* wz1 = (const float*)d_in[21];
    const float* bz1 = (const float*)d_in[22];
    const float* wz2 = (const float*)d_in[23];
    const float* bz2 = (const float*)d_in[24];
    const float* wt1 = (const float*)d_in[25];
    const float* bt1 = (const float*)d_in[26];
    const float* wt2 = (const float*)d_in[27];
    const float* bt2 = (const float*)d_in[28];

    char* ws = (char*)d_ws;
    short* WB1  = (short*)(ws);                  // 512 KB
    short* WB2  = (short*)(ws + 524288);         // 320 KB
    float* xe   = (float*)(ws + 851968);         // 64 KB
    float* h2o  = (float*)(ws + 917504);         // 128 KB
    int*   syncp= (int*)(ws + 1048576);          // 256 B (memset to 0)
    short* yfr  = (short*)(ws + 2097152);        // 67.1 MB
    float* out  = (float*)d_out;

    // chunk size from workspace: need fixed + 2*(xg + yg chunk buffers) + slack
    int TC = 32;
    if (69206016ull + 2ull * 64 * 524288 + 2ull * 64 * 262144 + 65536 <= ws_size) TC = 64;
    const int NC = 512 / TC;
    const size_t xgS = (size_t)TC * 262144;   // shorts per xg buffer
    const size_t ygS = (size_t)TC * 131072;   // shorts per yg buffer
    short* xgA = (short*)(ws + 69206016);
    short* xgB = xgA + xgS;
    short* ygA = xgB + xgS;
    short* ygB = ygA + ygS;

    hipMemsetAsync(syncp, 0, 256, stream);
    prep_embed_kernel<<<1280, 256, 0, stream>>>(k1f, r1f, k1b, r1b, k2f, r2f, k2b, r2b,
                                                WB1, WB2, inputA, emb, w1, b1, w2, b2, w3, b3, xe);
    persist_kernel<<<NBLK, 512, 0, stream>>>(inputB, WB1, WB2, bb1f, bb1b, bb2f, bb2b,
                                             yfr, xgA, xgB, ygA, ygB, h2o, syncp, TC, NC);
    heads_kernel<<<1, 256, 0, stream>>>(xe, h2o, wz1, bz1, wz2, bz2, wt1, bt1, wt2, bt2, out);
}

// Round 8
// 672.860 us; speedup vs baseline: 2.1155x; 2.1155x over previous
//
#include <hip/hip_runtime.h>

typedef __attribute__((ext_vector_type(8))) short s8v;
typedef __attribute__((ext_vector_type(4))) short s4v;
typedef __attribute__((ext_vector_type(4))) float f4v;

#if __has_builtin(__builtin_amdgcn_exp2f)
#define EXP2(x) __builtin_amdgcn_exp2f(x)
#else
#define EXP2(x) exp2f(x)
#endif
#if __has_builtin(__builtin_amdgcn_rcpf)
#define RCP(x) __builtin_amdgcn_rcpf(x)
#else
#define RCP(x) (1.0f/(x))
#endif

#define LOG2E 1.4426950408889634f

__device__ __forceinline__ short f2bf(float f) {
    union { float f; unsigned u; } x; x.f = f;
    unsigned r = (x.u + 0x7FFFu + ((x.u >> 16) & 1u)) >> 16;
    return (short)r;
}
__device__ __forceinline__ float bf2f(short s) {
    union { unsigned u; float f; } x; x.u = ((unsigned)(unsigned short)s) << 16;
    return x.f;
}
// LDS-visibility barrier WITHOUT vmcnt drain (keeps prefetch/stores in flight).
__device__ __forceinline__ void lds_barrier() {
    asm volatile("s_waitcnt lgkmcnt(0)\n\ts_barrier" ::: "memory");
}

// ---------------- prep (weights->bf16 B-frag, sigmoid pre-scale) + embed MLP, fused ----------------
__global__ __launch_bounds__(256) void prep_embed_kernel(
        const float* __restrict__ k1f, const float* __restrict__ r1f,
        const float* __restrict__ k1b, const float* __restrict__ r1b,
        const float* __restrict__ k2f, const float* __restrict__ r2f,
        const float* __restrict__ k2b, const float* __restrict__ r2b,
        short* __restrict__ WB1, short* __restrict__ WB2,
        const int* __restrict__ inputA, const float* __restrict__ emb,
        const float* __restrict__ w1, const float* __restrict__ b1,
        const float* __restrict__ w2, const float* __restrict__ b2,
        const float* __restrict__ w3, const float* __restrict__ b3,
        float* __restrict__ xe) {
    if (blockIdx.x < 1024) {
        int idx = blockIdx.x * 256 + threadIdx.x;
        if (idx < 262144) {  // 2*32*8*64*8
            int j = idx & 7, l = (idx >> 3) & 63, c = (idx >> 9) & 7, n = (idx >> 12) & 31, d = (idx >> 17) & 1;
            int coln = n * 16 + (l & 15);
            int k = c * 32 + ((l >> 4) * 8) + j;
            const float* Wk = d ? k1b : k1f;
            const float* Wr = d ? r1b : r1f;
            float v = (c < 4) ? Wk[k * 512 + coln] : Wr[(k - 128) * 512 + coln];
            float sc = ((n >> 3) == 2) ? 1.0f : -LOG2E;  // gate: 0=i,1=f,2=cc,3=o
            WB1[idx] = f2bf(v * sc);
        }
        if (idx < 163840) {  // 2*16*10*64*8
            int d = idx / 81920, r0 = idx % 81920;
            int n = r0 / 5120, r1 = r0 % 5120;
            int c = r1 / 512, li = r1 % 512;
            int l = li >> 3, j = li & 7;
            int coln = n * 16 + (l & 15);
            int k = c * 32 + ((l >> 4) * 8) + j;
            const float* Wk = d ? k2b : k2f;
            const float* Wr = d ? r2b : r2f;
            float v = (k < 256) ? Wk[k * 256 + coln] : Wr[(k - 256) * 256 + coln];
            float sc = ((n >> 2) == 2) ? 1.0f : -LOG2E;
            WB2[idx] = f2bf(v * sc);
        }
        return;
    }
    __shared__ float row[600];
    __shared__ float h1[256];
    __shared__ float h2[128];
    int b = blockIdx.x - 1024, t = threadIdx.x;
    if (t < 200) {
        int idx = inputA[b * 200 + t];
        row[t * 3 + 0] = emb[idx * 3 + 0];
        row[t * 3 + 1] = emb[idx * 3 + 1];
        row[t * 3 + 2] = emb[idx * 3 + 2];
    }
    __syncthreads();
    float a = b1[t];
    for (int k = 0; k < 600; k++) a += row[k] * w1[k * 256 + t];
    h1[t] = fmaxf(a, 0.f);
    __syncthreads();
    if (t < 128) {
        float a2 = b2[t];
        for (int k = 0; k < 256; k++) a2 += h1[k] * w2[k * 128 + t];
        h2[t] = fmaxf(a2, 0.f);
    }
    __syncthreads();
    if (t < 64) {
        float a3 = b3[t];
        for (int k = 0; k < 128; k++) a3 += h2[k] * w3[k * 64 + t];
        xe[b * 64 + t] = fmaxf(a3, 0.f);
    }
}

// ---------------- megastep: one pipeline super-step per launch ----------------
// 86KB static LDS per block (hA+hB+stg, all genuinely referenced) -> any two blocks
// exceed 160KB/CU -> HW guarantees 1 block/CU. Recurrence blocks (0..63) dispatch
// first and own their CUs; gemm blocks fill the rest. Kernel boundary = grid sync
// + cross-XCD coherence (no fences needed).
// launch k: lstm1(k-1) | lstm2(k-3) | gemm1(k) | gemm2(k-2); chunk c in buffer (c&1).
__global__ __launch_bounds__(512, 2) void megastep(
        const float* __restrict__ x, const short* __restrict__ WB1, const short* __restrict__ WB2,
        const float* __restrict__ bb1f, const float* __restrict__ bb1b,
        const float* __restrict__ bb2f, const float* __restrict__ bb2b,
        short* __restrict__ yfr, short* __restrict__ xgA, short* __restrict__ xgB,
        short* __restrict__ ygA, short* __restrict__ ygB,
        float* __restrict__ c1st, short* __restrict__ h1st,
        float* __restrict__ c2st, short* __restrict__ h2st,
        float* __restrict__ h2o, int k, int TC, int NC) {
    __shared__ short hA[2048];      // 4KB
    __shared__ short hB[2048];      // 4KB
    __shared__ short stg[38912];    // 76KB (gemm1 uses first 32KB; rest = occupancy pad)
    const int tid = threadIdx.x, lane = tid & 63, w = tid >> 6;
    const int bid = blockIdx.x;
    const int tgn = TC >> 3;

    if (bid < 32) {
        // ================= LSTM1 role: chunk cl = k-1 =================
        const int cl = k - 1;
        if (cl < 0 || cl >= NC) return;
        const int t0 = cl * TC;
        const int first = (cl == 0);
        const int btile = bid & 15, dir = bid >> 4;
        const int col = lane & 15, q = lane >> 4, u = (w << 4) + col;
        const int sb = dir * 16 + btile;

        s8v wf[4][4];  // h-part chunks 4..7
#pragma unroll
        for (int ti = 0; ti < 4; ti++)
#pragma unroll
            for (int c = 0; c < 4; c++)
                wf[ti][c] = *(const s8v*)(WB1 + ((((dir * 32 + (w + 8 * ti)) * 8) + 4 + c) * 64 + lane) * 8);

        float cst[4], hl[4];
        if (first) {
#pragma unroll
            for (int r = 0; r < 4; r++) cst[r] = 0.f;
            for (int i = tid; i < 2048; i += 512) hA[i] = 0;
        } else {
            f4v cv = *(const f4v*)(c1st + ((size_t)sb * 8 + w) * 256 + lane * 4);
#pragma unroll
            for (int r = 0; r < 4; r++) cst[r] = cv[r];
            for (int i = tid; i < 2048; i += 512) hA[i] = h1st[sb * 2048 + i];
        }
        __syncthreads();

        const short* xgp = ((cl & 1) ? xgB : xgA) + (size_t)sb * TC * 8192 + w * 1024 + lane * 8;
        s8v pe0 = *(const s8v*)(xgp);
        s8v pe1 = *(const s8v*)(xgp + 512);
        s8v po0 = *(const s8v*)(xgp + 8192);
        s8v po1 = *(const s8v*)(xgp + 8192 + 512);

        const int hidx = (w >> 1) * 512 + ((u >> 3) & 3) * 128 + (u & 7);

        for (int s = 0; s < TC; s += 2) {
            {   // even step: read hA, write hB
                s8v ah[4];
#pragma unroll
                for (int cc = 0; cc < 4; cc++) ah[cc] = *(const s8v*)&hA[(cc * 64 + lane) * 8];
                if (w >= 4 && s > 0) {
                    int tp = t0 + s - 1;
                    if (dir) tp = 511 - tp;
                    s8v hv = (w == 4) ? ah[0] : (w == 5) ? ah[1] : (w == 6) ? ah[2] : ah[3];
                    *(s8v*)(yfr + (((size_t)(btile * 512 + tp) * 8) + dir * 4 + (w - 4)) * 512 + lane * 8) = hv;
                }
                f4v acc[4];
#pragma unroll
                for (int r = 0; r < 4; r++) {
                    acc[0][r] = bf2f(pe0[r]);
                    acc[1][r] = bf2f(pe0[4 + r]);
                    acc[2][r] = bf2f(pe1[r]);
                    acc[3][r] = bf2f(pe1[4 + r]);
                }
                {
                    const short* np = xgp + (size_t)(s + 2) * 8192;
                    pe0 = *(const s8v*)np;
                    pe1 = *(const s8v*)(np + 512);
                }
#pragma unroll
                for (int cc = 0; cc < 4; cc++)
#pragma unroll
                    for (int ti = 0; ti < 4; ti++)
                        acc[ti] = __builtin_amdgcn_mfma_f32_16x16x32_bf16(ah[cc], wf[ti][cc], acc[ti], 0, 0, 0);
#pragma unroll
                for (int r = 0; r < 4; r++) {
                    float iv = RCP(1.0f + EXP2(acc[0][r]));
                    float fv = RCP(1.0f + EXP2(acc[1][r]));
                    float ov = RCP(1.0f + EXP2(acc[3][r]));
                    float ccv = fmaxf(acc[2][r], 0.f);
                    cst[r] = fv * cst[r] + iv * ccv;
                    hl[r] = ov * fmaxf(cst[r], 0.f);
                }
#pragma unroll
                for (int r = 0; r < 4; r++)
                    hB[hidx + ((q * 4 + r) << 3)] = f2bf(hl[r]);
                lds_barrier();
            }
            {   // odd step: read hB, write hA
                s8v ah[4];
#pragma unroll
                for (int cc = 0; cc < 4; cc++) ah[cc] = *(const s8v*)&hB[(cc * 64 + lane) * 8];
                if (w >= 4) {
                    int tp = t0 + s;
                    if (dir) tp = 511 - tp;
                    s8v hv = (w == 4) ? ah[0] : (w == 5) ? ah[1] : (w == 6) ? ah[2] : ah[3];
                    *(s8v*)(yfr + (((size_t)(btile * 512 + tp) * 8) + dir * 4 + (w - 4)) * 512 + lane * 8) = hv;
                }
                f4v acc[4];
#pragma unroll
                for (int r = 0; r < 4; r++) {
                    acc[0][r] = bf2f(po0[r]);
                    acc[1][r] = bf2f(po0[4 + r]);
                    acc[2][r] = bf2f(po1[r]);
                    acc[3][r] = bf2f(po1[4 + r]);
                }
                {
                    const short* np = xgp + (size_t)(s + 3) * 8192;
                    po0 = *(const s8v*)np;
                    po1 = *(const s8v*)(np + 512);
                }
#pragma unroll
                for (int cc = 0; cc < 4; cc++)
#pragma unroll
                    for (int ti = 0; ti < 4; ti++)
                        acc[ti] = __builtin_amdgcn_mfma_f32_16x16x32_bf16(ah[cc], wf[ti][cc], acc[ti], 0, 0, 0);
#pragma unroll
                for (int r = 0; r < 4; r++) {
                    float iv = RCP(1.0f + EXP2(acc[0][r]));
                    float fv = RCP(1.0f + EXP2(acc[1][r]));
                    float ov = RCP(1.0f + EXP2(acc[3][r]));
                    float ccv = fmaxf(acc[2][r], 0.f);
                    cst[r] = fv * cst[r] + iv * ccv;
                    hl[r] = ov * fmaxf(cst[r], 0.f);
                }
#pragma unroll
                for (int r = 0; r < 4; r++)
                    hA[hidx + ((q * 4 + r) << 3)] = f2bf(hl[r]);
                lds_barrier();
            }
        }
        if (w >= 4) {  // final h(TC-1)
            int tp = t0 + TC - 1;
            if (dir) tp = 511 - tp;
            s8v hv = *(const s8v*)&hA[((w - 4) * 64 + lane) * 8];
            *(s8v*)(yfr + (((size_t)(btile * 512 + tp) * 8) + dir * 4 + (w - 4)) * 512 + lane * 8) = hv;
        }
        f4v cv;
#pragma unroll
        for (int r = 0; r < 4; r++) cv[r] = cst[r];
        *(f4v*)(c1st + ((size_t)sb * 8 + w) * 256 + lane * 4) = cv;
        for (int i = tid; i < 2048; i += 512) h1st[sb * 2048 + i] = hA[i];
        return;
    }

    if (bid < 64) {
        // ================= LSTM2 role: chunk c2 = k-3 (waves 0-3 compute) =================
        const int c2 = k - 3;
        if (c2 < 0 || c2 >= NC) return;
        const int first = (c2 == 0), last = (c2 == NC - 1);
        const int btile = (bid - 32) & 15, dir = (bid - 32) >> 4;
        const int b0 = btile << 4;
        const int w4 = w & 3;
        const int col = lane & 15, q = lane >> 4, u = (w4 << 4) + col;
        const int sb = dir * 16 + btile;

        s8v wf[4][2];  // h-part chunks 8,9
#pragma unroll
        for (int ti = 0; ti < 4; ti++)
#pragma unroll
            for (int c = 0; c < 2; c++)
                wf[ti][c] = *(const s8v*)(WB2 + ((((dir * 16 + (w4 + 4 * ti)) * 10) + 8 + c) * 64 + lane) * 8);

        float cst[4], hl[4] = {0.f, 0.f, 0.f, 0.f};
        if (first) {
#pragma unroll
            for (int r = 0; r < 4; r++) cst[r] = 0.f;
            for (int i = tid; i < 1024; i += 512) hA[i] = 0;
        } else {
            f4v cv = *(const f4v*)(c2st + ((size_t)sb * 4 + w4) * 256 + lane * 4);
#pragma unroll
            for (int r = 0; r < 4; r++) cst[r] = cv[r];
            for (int i = tid; i < 1024; i += 512) hA[i] = h2st[sb * 1024 + i];
        }
        __syncthreads();

        const short* ygp = ((c2 & 1) ? ygB : ygA) + (size_t)sb * TC * 4096 + w4 * 1024 + lane * 8;
        s8v pe0, pe1, po0, po1;
        if (w < 4) {
            pe0 = *(const s8v*)(ygp);
            pe1 = *(const s8v*)(ygp + 512);
            po0 = *(const s8v*)(ygp + 4096);
            po1 = *(const s8v*)(ygp + 4096 + 512);
        }
        const int hidx = (w4 >> 1) * 512 + ((u >> 3) & 3) * 128 + (u & 7);

        for (int s = 0; s < TC; s += 2) {
            if (w < 4) {  // even: read hA, write hB
                s8v ah[2];
#pragma unroll
                for (int cc = 0; cc < 2; cc++) ah[cc] = *(const s8v*)&hA[(cc * 64 + lane) * 8];
                f4v acc[4];
#pragma unroll
                for (int r = 0; r < 4; r++) {
                    acc[0][r] = bf2f(pe0[r]);
                    acc[1][r] = bf2f(pe0[4 + r]);
                    acc[2][r] = bf2f(pe1[r]);
                    acc[3][r] = bf2f(pe1[4 + r]);
                }
                {
                    const short* np = ygp + (size_t)(s + 2) * 4096;
                    pe0 = *(const s8v*)np;
                    pe1 = *(const s8v*)(np + 512);
                }
#pragma unroll
                for (int cc = 0; cc < 2; cc++)
#pragma unroll
                    for (int ti = 0; ti < 4; ti++)
                        acc[ti] = __builtin_amdgcn_mfma_f32_16x16x32_bf16(ah[cc], wf[ti][cc], acc[ti], 0, 0, 0);
#pragma unroll
                for (int r = 0; r < 4; r++) {
                    float iv = RCP(1.0f + EXP2(acc[0][r]));
                    float fv = RCP(1.0f + EXP2(acc[1][r]));
                    float ov = RCP(1.0f + EXP2(acc[3][r]));
                    float ccv = fmaxf(acc[2][r], 0.f);
                    cst[r] = fv * cst[r] + iv * ccv;
                    hl[r] = ov * fmaxf(cst[r], 0.f);
                }
#pragma unroll
                for (int r = 0; r < 4; r++)
                    hB[hidx + ((q * 4 + r) << 3)] = f2bf(hl[r]);
            }
            lds_barrier();
            if (w < 4) {  // odd: read hB, write hA
                s8v ah[2];
#pragma unroll
                for (int cc = 0; cc < 2; cc++) ah[cc] = *(const s8v*)&hB[(cc * 64 + lane) * 8];
                f4v acc[4];
#pragma unroll
                for (int r = 0; r < 4; r++) {
                    acc[0][r] = bf2f(po0[r]);
                    acc[1][r] = bf2f(po0[4 + r]);
                    acc[2][r] = bf2f(po1[r]);
                    acc[3][r] = bf2f(po1[4 + r]);
                }
                {
                    const short* np = ygp + (size_t)(s + 3) * 4096;
                    po0 = *(const s8v*)np;
                    po1 = *(const s8v*)(np + 512);
                }
#pragma unroll
                for (int cc = 0; cc < 2; cc++)
#pragma unroll
                    for (int ti = 0; ti < 4; ti++)
                        acc[ti] = __builtin_amdgcn_mfma_f32_16x16x32_bf16(ah[cc], wf[ti][cc], acc[ti], 0, 0, 0);
#pragma unroll
                for (int r = 0; r < 4; r++) {
                    float iv = RCP(1.0f + EXP2(acc[0][r]));
                    float fv = RCP(1.0f + EXP2(acc[1][r]));
                    float ov = RCP(1.0f + EXP2(acc[3][r]));
                    float ccv = fmaxf(acc[2][r], 0.f);
                    cst[r] = fv * cst[r] + iv * ccv;
                    hl[r] = ov * fmaxf(cst[r], 0.f);
                }
#pragma unroll
                for (int r = 0; r < 4; r++)
                    hA[hidx + ((q * 4 + r) << 3)] = f2bf(hl[r]);
            }
            lds_barrier();
        }
        if (w < 4) {
            f4v cv;
#pragma unroll
            for (int r = 0; r < 4; r++) cv[r] = cst[r];
            *(f4v*)(c2st + ((size_t)sb * 4 + w4) * 256 + lane * 4) = cv;
        }
        __syncthreads();
        for (int i = tid; i < 1024; i += 512) h2st[sb * 1024 + i] = hA[i];
        if (last && w < 4) {
#pragma unroll
            for (int r = 0; r < 4; r++)
                h2o[((dir * 256) + b0 + q * 4 + r) * 64 + u] = hl[r];
        }
        return;
    }

    if (bid < 64 + 4 * TC) {
        // ================= GEMM1 role: xg(k) = x @ Wk + b =================
        const int cg = k;
        if (cg >= NC) return;
        const int t0 = cg * TC;
        const int g = bid - 64;
        const int btile = g & 15;
        const int rest = g >> 4;
        const int tg = rest % tgn;
        const int dir = rest / tgn;
        const int b0 = btile << 4;
        short* xg_w = (cg & 1) ? xgB : xgA;
        {   // stage A frags for slice sl = w (coalesced 512B segments + XOR swizzle)
            int tglob = t0 + tg * 8 + w;
            if (dir) tglob = 511 - tglob;
            const int half = lane >> 5;
            const int f0 = (lane & 31) * 4;
            const int cx = f0 >> 5, qq = (f0 >> 3) & 3, j0 = f0 & 7;
#pragma unroll
            for (int rr = 0; rr < 8; rr++) {
                const int m = rr * 2 + half;
                const float* xp = x + ((size_t)(b0 + m) * 512 + tglob) * 128 + f0;
                f4v v4 = *(const f4v*)xp;
                const int slot = (qq << 4) | ((m ^ qq ^ (cx << 1)) & 15);
                s4v pk;
#pragma unroll
                for (int j = 0; j < 4; j++) pk[j] = f2bf(v4[j]);
                *(s4v*)&stg[(((w * 4 + cx) * 64 + slot) * 8) + j0] = pk;
            }
        }
        s8v wf[4][4];
#pragma unroll
        for (int ti = 0; ti < 4; ti++)
#pragma unroll
            for (int c = 0; c < 4; c++)
                wf[ti][c] = *(const s8v*)(WB1 + ((((dir * 32 + (w + 8 * ti)) * 8) + c) * 64 + lane) * 8);
        const float* bb = dir ? bb1b : bb1f;
        float bias[4];
#pragma unroll
        for (int ti = 0; ti < 4; ti++) {
            const int tile = w + 8 * ti;
            float sc = ((tile >> 3) == 2) ? 1.0f : -LOG2E;
            bias[ti] = sc * bb[tile * 16 + (lane & 15)];
        }
        __syncthreads();
        const size_t sb = dir * 16 + btile;
#pragma unroll 2
        for (int sl = 0; sl < 8; sl++) {
            s8v a[4];
#pragma unroll
            for (int c = 0; c < 4; c++) {
                const int slot = lane ^ (lane >> 4) ^ (c << 1);
                a[c] = *(const s8v*)&stg[((sl * 4 + c) * 64 + slot) * 8];
            }
            f4v acc[4];
#pragma unroll
            for (int ti = 0; ti < 4; ti++) { f4v z = {0.f, 0.f, 0.f, 0.f}; acc[ti] = z; }
#pragma unroll
            for (int c = 0; c < 4; c++)
#pragma unroll
                for (int ti = 0; ti < 4; ti++)
                    acc[ti] = __builtin_amdgcn_mfma_f32_16x16x32_bf16(a[c], wf[ti][c], acc[ti], 0, 0, 0);
            short* outp = xg_w + ((sb * TC + (size_t)(tg * 8 + sl)) * 8 + w) * 1024 + lane * 8;
#pragma unroll
            for (int p = 0; p < 2; p++) {
                s8v v;
#pragma unroll
                for (int j = 0; j < 4; j++) {
                    v[j]     = f2bf(acc[2 * p][j]     + bias[2 * p]);
                    v[4 + j] = f2bf(acc[2 * p + 1][j] + bias[2 * p + 1]);
                }
                *(s8v*)(outp + p * 512) = v;
            }
        }
        return;
    }

    // ================= GEMM2 role: yg(k-2) = y @ Wk2 + b =================
    {
        const int cg = k - 2;
        if (cg < 0 || cg >= NC) return;
        const int t0 = cg * TC;
        const int g = bid - 64 - 4 * TC;
        const int btile = g & 15;
        const int rest = g >> 4;
        const int tg = rest % tgn;
        const int dir = rest / tgn;
        short* yg_w = (cg & 1) ? ygB : ygA;
        const int w4 = w & 3, sh = (w >> 2) * 4;
        s8v wf[4][8];
#pragma unroll
        for (int ti = 0; ti < 4; ti++)
#pragma unroll
            for (int c = 0; c < 8; c++)
                wf[ti][c] = *(const s8v*)(WB2 + ((((dir * 16 + (w4 + 4 * ti)) * 10) + c) * 64 + lane) * 8);
        const float* bb = dir ? bb2b : bb2f;
        float bias[4];
#pragma unroll
        for (int ti = 0; ti < 4; ti++) {
            const int tile = w4 + 4 * ti;
            float sc = ((tile >> 2) == 2) ? 1.0f : -LOG2E;
            bias[ti] = sc * bb[tile * 16 + (lane & 15)];
        }
        const size_t sb = dir * 16 + btile;
#pragma unroll
        for (int si = 0; si < 4; si++) {
            const int sl = sh + si;
            int tglob = t0 + tg * 8 + sl;
            if (dir) tglob = 511 - tglob;
            s8v a[8];
#pragma unroll
            for (int c = 0; c < 8; c++)
                a[c] = *(const s8v*)(yfr + (((size_t)(btile * 512 + tglob) * 8) + c) * 512 + lane * 8);
            f4v acc[4];
#pragma unroll
            for (int ti = 0; ti < 4; ti++) { f4v z = {0.f, 0.f, 0.f, 0.f}; acc[ti] = z; }
#pragma unroll
            for (int c = 0; c < 8; c++)
#pragma unroll
                for (int ti = 0; ti < 4; ti++)
                    acc[ti] = __builtin_amdgcn_mfma_f32_16x16x32_bf16(a[c], wf[ti][c], acc[ti], 0, 0, 0);
            short* outp = yg_w + ((sb * TC + (size_t)(tg * 8 + sl)) * 4 + w4) * 1024 + lane * 8;
#pragma unroll
            for (int p = 0; p < 2; p++) {
                s8v v;
#pragma unroll
                for (int j = 0; j < 4; j++) {
                    v[j]     = f2bf(acc[2 * p][j]     + bias[2 * p]);
                    v[4 + j] = f2bf(acc[2 * p + 1][j] + bias[2 * p + 1]);
                }
                *(s8v*)(outp + p * 512) = v;
            }
        }
    }
}

// ---------------- final heads (fp32) ----------------
__global__ void heads_kernel(const float* __restrict__ xe, const float* __restrict__ h2o,
                             const float* __restrict__ wz1, const float* __restrict__ bz1,
                             const float* __restrict__ wz2, const float* __restrict__ bz2,
                             const float* __restrict__ wt1, const float* __restrict__ bt1,
                             const float* __restrict__ wt2, const float* __restrict__ bt2,
                             float* __restrict__ out) {
    int b = threadIdx.x;  // 256 threads, 1 block
    float cz0 = bz1[0], cz1 = bz1[1], ct0 = bt1[0], ct1 = bt1[1];
    for (int k = 0; k < 192; k++) {
        float v = (k < 64) ? xe[b * 64 + k]
                : (k < 128) ? h2o[b * 64 + (k - 64)]
                            : h2o[(256 + b) * 64 + (k - 128)];
        cz0 += v * wz1[k * 2 + 0];
        cz1 += v * wz1[k * 2 + 1];
        ct0 += v * wt1[k * 2 + 0];
        ct1 += v * wt1[k * 2 + 1];
    }
    cz0 = fmaxf(cz0, 0.f); cz1 = fmaxf(cz1, 0.f);
    ct0 = fmaxf(ct0, 0.f); ct1 = fmaxf(ct1, 0.f);
    out[b] = cz0 * wz2[0] + cz1 * wz2[1] + bz2[0];
    out[256 + b] = ct0 * wt2[0] + ct1 * wt2[1] + bt2[0];
}

extern "C" void kernel_launch(void* const* d_in, const int* in_sizes, int n_in,
                              void* d_out, int out_size, void* d_ws, size_t ws_size,
                              hipStream_t stream) {
    const int*   inputA = (const int*)d_in[0];
    const float* inputB = (const float*)d_in[1];
    const float* emb = (const float*)d_in[2];
    const float* w1  = (const float*)d_in[3];
    const float* b1  = (const float*)d_in[4];
    const float* w2  = (const float*)d_in[5];
    const float* b2  = (const float*)d_in[6];
    const float* w3  = (const float*)d_in[7];
    const float* b3  = (const float*)d_in[8];
    const float* k1f = (const float*)d_in[9];
    const float* r1f = (const float*)d_in[10];
    const float* bb1f= (const float*)d_in[11];
    const float* k1b = (const float*)d_in[12];
    const float* r1b = (const float*)d_in[13];
    const float* bb1b= (const float*)d_in[14];
    const float* k2f = (const float*)d_in[15];
    const float* r2f = (const float*)d_in[16];
    const float* bb2f= (const float*)d_in[17];
    const float* k2b = (const float*)d_in[18];
    const float* r2b = (const float*)d_in[19];
    const float* bb2b= (const float*)d_in[20];
    const float* wz1 = (const float*)d_in[21];
    const float* bz1 = (const float*)d_in[22];
    const float* wz2 = (const float*)d_in[23];
    const float* bz2 = (const float*)d_in[24];
    const float* wt1 = (const float*)d_in[25];
    const float* bt1 = (const float*)d_in[26];
    const float* wt2 = (const float*)d_in[27];
    const float* bt2 = (const float*)d_in[28];

    char* ws = (char*)d_ws;
    short* WB1  = (short*)(ws);                  // 512 KB
    short* WB2  = (short*)(ws + 524288);         // 320 KB
    float* xe   = (float*)(ws + 851968);         // 64 KB
    float* h2o  = (float*)(ws + 917504);         // 128 KB
    float* c1st = (float*)(ws + 1048576);        // 256 KB
    short* h1st = (short*)(ws + 1310720);        // 128 KB
    float* c2st = (float*)(ws + 1441792);        // 128 KB
    short* h2st = (short*)(ws + 1572864);        // 64 KB
    short* yfr  = (short*)(ws + 2097152);        // 67.1 MB
    float* out  = (float*)d_out;

    // chunk size: need fixed + 2*xg + 2*yg + slack
    int TC = 32;
    if (69206016ull + 2ull * 64 * 524288 + 2ull * 64 * 262144 + 65536 <= ws_size) TC = 64;
    const int NC = 512 / TC;
    short* xgA = (short*)(ws + 69206016);
    short* xgB = xgA + (size_t)TC * 262144;
    short* ygA = xgB + (size_t)TC * 262144;
    short* ygB = ygA + (size_t)TC * 131072;
    const int grid = 64 + 8 * TC;  // 64 recurrence + 4*TC gemm1 + 4*TC gemm2

    prep_embed_kernel<<<1280, 256, 0, stream>>>(k1f, r1f, k1b, r1b, k2f, r2f, k2b, r2b,
                                                WB1, WB2, inputA, emb, w1, b1, w2, b2, w3, b3, xe);
    for (int k = 0; k < NC + 3; k++) {
        megastep<<<grid, 512, 0, stream>>>(inputB, WB1, WB2, bb1f, bb1b, bb2f, bb2b,
                                           yfr, xgA, xgB, ygA, ygB,
                                           c1st, h1st, c2st, h2st, h2o, k, TC, NC);
    }
    heads_kernel<<<1, 256, 0, stream>>>(xe, h2o, wz1, bz1, wz2, bz2, wt1, bt1, wt2, bt2, out);
}